// Round 11
// baseline (376.646 us; speedup 1.0000x reference)
//
#include <hip/hip_runtime.h>

// MHA forward: x(2,2048,2048) fp32, Wq/Wk/Wv/Wo (2048,2048) fp32 -> out fp32.
// R14: GEMM K-loop -> counted-vmcnt half-tile pipeline (m201-style T3+T4).
//      Ring of 4 half-tile buffers (32 cols each, same 114.7KB LDS), staged
//      3 halves ahead; per-wave load ledger arranged so any 2 consecutive
//      halves = 7 loads (MODE0; 6 for MODE1) -> steady s_waitcnt vmcnt(7/6),
//      never draining to 0 until the tail. Half layout is linear (unit =
//      16 rows x 64B): no swizzle needed for staging or ds_read_b128.
//      setprio(1) around MFMA clusters. Natural dim3 grid kept (XCD-resident
//      B panels). Attention (R13 swapped-QK^T) and cvt unchanged.

#define SEQ 2048
#define DMODEL 2048
#define NH 16
#define HD 128

typedef __attribute__((ext_vector_type(8))) short bf16x8;  // 8 bf16 = 4 VGPRs
typedef __attribute__((ext_vector_type(4))) float f32x4;

__device__ __forceinline__ unsigned short f2bf(float f) {  // RNE fp32->bf16
  unsigned int u = __float_as_uint(f);
  u += 0x7fffu + ((u >> 16) & 1u);
  return (unsigned short)(u >> 16);
}

__device__ __forceinline__ void g2l16(const void* g, void* l) {
  __builtin_amdgcn_global_load_lds((const __attribute__((address_space(1))) void*)g,
                                   (__attribute__((address_space(3))) void*)l,
                                   16, 0, 0);
}

__device__ __forceinline__ f32x4 mfma16(bf16x8 a, bf16x8 b, f32x4 c) {
  return __builtin_amdgcn_mfma_f32_16x16x32_bf16(a, b, c, 0, 0, 0);
}

// one launch: converts x + all four weights to bf16, permutes Wq/Wk rows
// within-head (RoPE pairs -> adjacent 16-col fragments), fills rope table.
__global__ __launch_bounds__(256) void cvt_all(const float* __restrict__ x,
                                               const float* __restrict__ wq,
                                               const float* __restrict__ wk,
                                               const float* __restrict__ wv,
                                               const float* __restrict__ wo,
                                               unsigned short* __restrict__ dst0,
                                               float2* __restrict__ rtab) {
  const int b = blockIdx.x;
  if (b >= 24576) {  // rope cos/sin table: 2048 x 64
    const int idx = (b - 24576) * 256 + threadIdx.x;  // [0, 131072)
    const int s = idx >> 6, d = idx & 63;
    float sn, cs;
    sincosf((float)s * exp2f(-0.20762050593046f * (float)d), &sn, &cs);
    rtab[idx] = make_float2(cs, sn);
    return;
  }
  const float* src;
  unsigned short* dst;
  int idx, r = -1;
  if (b < 8192) {  // x: 2097152 float4's
    src = x; dst = dst0; idx = b * 256 + threadIdx.x;
  } else {
    r = (b - 8192) >> 12;  // 4096 blocks per weight
    src = (r == 0) ? wq : (r == 1) ? wk : (r == 2) ? wv : wo;
    dst = dst0 + (size_t)2 * SEQ * DMODEL + (size_t)r * DMODEL * DMODEL;
    idx = ((b - 8192) & 4095) * 256 + threadIdx.x;
  }
  const float4 v = ((const float4*)src)[idx];
  ushort4 o;
  o.x = f2bf(v.x); o.y = f2bf(v.y); o.z = f2bf(v.z); o.w = f2bf(v.w);
  int widx = idx;
  if (r == 0 || r == 1) {  // permute Wq/Wk output-feature rows within head
    const int row = idx >> 9, col = idx & 511;
    const int o_ = row & 127;
    const int e = (((o_ >> 4) & 3) << 5) | (((o_ >> 6) & 1) << 4) | (o_ & 15);
    widx = (((row & ~127) | e) << 9) | col;
  }
  ((ushort4*)dst)[widx] = o;
}

// ---------------------------------------------------------------------------
// Counted-vmcnt pipelined GEMM: C[m,n] = sum_k A[m,k]*B[n,k].
// BM=256, BN=192(MODE0)/128(MODE1). 512 threads = 8 waves (4M x 2N), wave
// tile 64 x BN/2. K processed in 64 halves of 32 cols; ring of 4 half-tile
// buffers (A 16KB + B BN*64B each). Staging unit = 16 rows x 64B (1KB),
// linear lane order (no swizzle); ds_read_b128 frags are contiguous-1KB
// permutations (conflict-free). Ledger: loads per wave over any 2 consecutive
// halves = 7 (MODE0: waves 0-3 stage {4,3} by parity, waves 4-7 {3,4}) or
// 6 (MODE1: uniform 3) -> steady s_waitcnt vmcnt(7/6); stage half i+3 while
// computing half i. Natural grid: blockIdx.x = nb (%8 -> XCD-resident B).
// ---------------------------------------------------------------------------
template <int MODE>
__global__ __launch_bounds__(512, 2) void gemm_pipe(
    const unsigned short* __restrict__ A,
    const unsigned short* __restrict__ B,
    unsigned short* __restrict__ obf,   // MODE0: qb (kb=+NX, vb=+2NX)
    float* __restrict__ of32,           // MODE1: output
    const float2* __restrict__ rtab) {
  constexpr int BN = (MODE == 0) ? 192 : 128;
  constexpr int NTW = BN / 32;            // B frags per wave: 6 / 4
  constexpr int HBUF = 8192 + BN * 32;    // shorts per half-buffer
  constexpr int NUA = 16;                 // A units (16 rows x 32 cols each)
  __shared__ unsigned short lds[4 * HBUF];
  const int nb = blockIdx.x, mb = blockIdx.y;
  const int M0 = mb * 256;
  const int t = threadIdx.x;
  const int w = t >> 6, lane = t & 63, l15 = lane & 15, quad = lane >> 4;
  const int g16 = lane >> 2, j4 = lane & 3;
  const int wm = w >> 1, wn = w & 1;

  const unsigned short* Abase = A + (size_t)M0 * DMODEL;
  const unsigned short* Bbase = B + (size_t)nb * BN * DMODEL;

  f32x4 acc[4][NTW] = {};

  // stage half h (k cols [h*32, h*32+32)) into ring buffer hb.
  auto stage_half = [&](int hb, int h) {
    int ub, cnt;
    if (MODE == 1) {
      ub = w * 3; cnt = 3;                     // 24 units, uniform
    } else if ((h & 1) == 0) {                 // even half: 4,4,4,4,3,3,3,3
      ub = (w < 4) ? w * 4 : 16 + (w - 4) * 3;
      cnt = (w < 4) ? 4 : 3;
    } else {                                   // odd half: 3,3,3,3,4,4,4,4
      ub = (w < 4) ? w * 3 : (w == 4 ? 12 : 16 + (w - 5) * 4);
      cnt = (w < 4) ? 3 : 4;
    }
#pragma unroll
    for (int i = 0; i < 4; ++i) {
      if (i < cnt) {
        const int u = ub + i;
        if (u < NUA) {
          g2l16(Abase + (size_t)(u * 16 + g16) * DMODEL + h * 32 + j4 * 8,
                &lds[hb * HBUF + u * 512]);
        } else {
          g2l16(Bbase + (size_t)((u - NUA) * 16 + g16) * DMODEL + h * 32 + j4 * 8,
                &lds[hb * HBUF + 8192 + (u - NUA) * 512]);
        }
      }
    }
  };

  // compute one half: 4+NTW ds_read_b128 + 4*NTW MFMA (k = quad*8 in-half)
  auto comp_half = [&](int hb) {
    const unsigned short* As_ = &lds[hb * HBUF];
    const unsigned short* Bs_ = &lds[hb * HBUF + 8192];
    bf16x8 af[4], bv[NTW];
#pragma unroll
    for (int mt = 0; mt < 4; ++mt)
      af[mt] = *(const bf16x8*)&As_[(wm * 64 + mt * 16 + l15) * 32 + quad * 8];
#pragma unroll
    for (int nt = 0; nt < NTW; ++nt)
      bv[nt] = *(const bf16x8*)&Bs_[(wn * (BN / 2) + nt * 16 + l15) * 32 + quad * 8];
    __builtin_amdgcn_s_setprio(1);
#pragma unroll
    for (int nt = 0; nt < NTW; ++nt)
#pragma unroll
      for (int mt = 0; mt < 4; ++mt)
        acc[mt][nt] = mfma16(af[mt], bv[nt], acc[mt][nt]);
    __builtin_amdgcn_s_setprio(0);
  };

  // prologue: halves 0,1,2 in flight; wait half 0 (2 halves = 7/6 remain)
  stage_half(0, 0);
  stage_half(1, 1);
  stage_half(2, 2);
  if (MODE == 0)
    asm volatile("s_waitcnt vmcnt(7)\n\ts_barrier" ::: "memory");
  else
    asm volatile("s_waitcnt vmcnt(6)\n\ts_barrier" ::: "memory");

  for (int i = 0; i < 64; ++i) {
    if (i < 61) stage_half((i + 3) & 3, i + 3);
    comp_half(i & 3);
    if (i < 61) {
      if (MODE == 0)
        asm volatile("s_waitcnt vmcnt(7)\n\ts_barrier" ::: "memory");
      else
        asm volatile("s_waitcnt vmcnt(6)\n\ts_barrier" ::: "memory");
    } else if (i == 61) {
      asm volatile("s_waitcnt vmcnt(3)\n\ts_barrier" ::: "memory");
    } else if (i == 62) {
      asm volatile("s_waitcnt vmcnt(0)\n\ts_barrier" ::: "memory");
    }
  }

  // Epilogue. C/D layout: col = l15 (N side), row = quad*4 + reg (M side).
  if (MODE == 0) {
    const size_t NX = (size_t)2 * SEQ * DMODEL;
#pragma unroll
    for (int pp = 0; pp < NTW / 2; ++pp) {
      const int colb = nb * BN + wn * (BN / 2) + pp * 32;  // 32-aligned
      const int z = colb >> 11;          // 0:Q 1:K 2:V
      const int zc = colb & 2047;
      const int h = zc >> 7;             // head
      const int e0 = zc & 127;           // in-head col base (0/32/64/96)
      if (z < 2) {
        const float qscale = (z == 0) ? 0.1275174356f : 1.0f;
        unsigned short* O = obf + (size_t)z * NX;
        const int rt = (e0 >> 5) * 16 + l15;  // rope dim q*16 + r
#pragma unroll
        for (int mt = 0; mt < 4; ++mt)
#pragma unroll
          for (int reg = 0; reg < 4; ++reg) {
            const int m = M0 + wm * 64 + mt * 16 + quad * 4 + reg;
            const int bb = m >> 11, s = m & 2047;
            unsigned short* ob = O + ((size_t)(bb * NH + h) * SEQ + s) * HD;
            const float2 cs = rtab[s * 64 + rt];
            const float x1 = acc[mt][2 * pp][reg], x2 = acc[mt][2 * pp + 1][reg];
            ob[e0 + l15] = f2bf((x1 * cs.x - x2 * cs.y) * qscale);
            ob[e0 + 16 + l15] = f2bf((x2 * cs.x + x1 * cs.y) * qscale);
          }
      } else {
        // V stored transposed: (B,H,hd,S), natural key order
        unsigned short* Vb0 = obf + 2 * NX + (size_t)h * HD * SEQ;
#pragma unroll
        for (int q2 = 0; q2 < 2; ++q2) {
          const int d = e0 + q2 * 16 + l15;
#pragma unroll
          for (int mt = 0; mt < 4; ++mt)
#pragma unroll
            for (int reg = 0; reg < 4; ++reg) {
              const int m = M0 + wm * 64 + mt * 16 + quad * 4 + reg;
              const int bb = m >> 11, s = m & 2047;
              unsigned short* ob = Vb0 + (size_t)bb * NH * HD * SEQ;
              ob[(size_t)d * SEQ + s] = f2bf(acc[mt][2 * pp + q2][reg]);
            }
        }
      }
    }
  } else {
#pragma unroll
    for (int mt = 0; mt < 4; ++mt)
#pragma unroll
      for (int reg = 0; reg < 4; ++reg) {
        const int m = M0 + wm * 64 + mt * 16 + quad * 4 + reg;
#pragma unroll
        for (int nt = 0; nt < NTW; ++nt)
          of32[(size_t)m * DMODEL + nb * BN + wn * (BN / 2) + nt * 16 + l15] =
              acc[mt][nt][reg];
      }
  }
}

// ---------------------------------------------------------------------------
// Flash attention, causal. QBLK=64 (4 waves x 16 rows), KVBLK=64, dbuf K/V.
// Block = one (b,h) x q-tile PAIR (pr, 31-pr): 33 kt-iters/block uniform.
// Grid 512 = 2 blocks/CU (72 KB LDS) -> co-resident blocks overlap stalls.
// SWAPPED QK^T: s[nt] = mfma(K-frag, Q-frag) -> lane holds S[key][q=l15],
// keys = nt*16 + quad*4 + reg. Softmax: in-lane tree + shfl_xor(16,32);
// m/l per-lane scalars (q=l15); alpha/l moved to O-layout (q=quad*4+reg)
// via __shfl(..,16). P: cvt_pk packs consecutive keys -> [16 q][32 u32],
// physcol = col ^ ((l15&7)<<2) (write 2-way, b128 read conflict-free).
// PV: A=P (row=l15=q), B=V natural keys. vmcnt(0)+barrier per iter.
// ---------------------------------------------------------------------------
__global__ __launch_bounds__(256) void attn_kernel(const unsigned short* __restrict__ Q,
                                                   const unsigned short* __restrict__ K,
                                                   const unsigned short* __restrict__ Vt,
                                                   unsigned short* __restrict__ Oa) {
  __shared__ unsigned short Ks[2][64 * 128];  // 2 x 16 KB
  __shared__ unsigned short Vs[2][128 * 64];  // 2 x 16 KB
  __shared__ unsigned short Ps[4][1024];      // 4 x 2 KB wave-private P
  const int gid = blockIdx.x;
  const int bh = gid & 31;   // all 16 pair-blocks of one bh on XCD bh%8
  const int pr = gid >> 5;   // pair index 0..15
  const unsigned short* Qb = Q + (size_t)bh * SEQ * HD;
  const unsigned short* Kb = K + (size_t)bh * SEQ * HD;
  const unsigned short* Vb = Vt + (size_t)bh * HD * SEQ;
  const int t = threadIdx.x;
  const int w = t >> 6, lane = t & 63, l15 = lane & 15, quad = lane >> 4;
  const int h7 = l15 & 7;
  const int b = bh >> 4, h = bh & 15;
  const int uA = w * 64 + lane;  // staging unit base (i*256 added per instr)

  // stage K/V tile kt into buffer sb: 256 threads x 4 instr x 16B per tensor.
  auto stage = [&](int sb, int kt) {
    const unsigned short* Kt = Kb + (size_t)(kt * 64) * HD;
    const unsigned short* Vtk = Vb + kt * 64;
#pragma unroll
    for (int i = 0; i < 4; ++i) {
      const int u = i * 256 + uA;
      const int key = u >> 4, cs = u & 15;
      g2l16(Kt + (size_t)key * HD + ((cs ^ (key & 7)) << 3), &Ks[sb][u * 8]);
    }
#pragma unroll
    for (int i = 0; i < 4; ++i) {
      const int u = i * 256 + uA;
      const int d = u >> 3, cs = u & 7;
      g2l16(Vtk + (size_t)d * SEQ + ((cs ^ (d & 7)) << 3), &Vs[sb][u * 8]);
    }
  };

  for (int half = 0; half < 2; ++half) {
    const int qt = half ? 31 - pr : pr;  // q-tile of 64 rows; kt = 0..qt

    // Q fragments (B-operand): col = q = l15, k(hd) = ch*32 + quad*8
    bf16x8 qf[4];
#pragma unroll
    for (int ch = 0; ch < 4; ++ch)
      qf[ch] = *(const bf16x8*)(Qb + (size_t)(qt * 64 + w * 16 + l15) * HD +
                                ch * 32 + quad * 8);

    f32x4 o[8] = {};
    float m_ = -1e30f, l_ = 0.f;  // per-lane: q-row = w*16 + l15

    stage(0, 0);
    asm volatile("s_waitcnt vmcnt(0)\n\ts_barrier" ::: "memory");
    int buf = 0;

    for (int kt = 0; kt <= qt; ++kt) {
      if (kt < qt) stage(buf ^ 1, kt + 1);  // prefetch next tile

      // Diagonal tile: key-tile nt fully masked iff nt > w.
      const bool diag = (kt == qt);
      const int ntm = diag ? w : 3;

      // S^T = K Q^T: s[nt][reg] = S[key = nt*16+quad*4+reg][q = w*16+l15]
      f32x4 s[4] = {};
      __builtin_amdgcn_s_setprio(1);
#pragma unroll
      for (int ch = 0; ch < 4; ++ch) {
        const int c = ch * 4 + quad;
#pragma unroll
        for (int nt = 0; nt < 4; ++nt) {
          if (nt <= ntm) {
            const int key = nt * 16 + l15;
            const bf16x8 kf = *(const bf16x8*)&Ks[buf][key * 128 + ((c ^ (key & 7)) << 3)];
            s[nt] = mfma16(kf, qf[ch], s[nt]);
          }
        }
      }
      __builtin_amdgcn_s_setprio(0);

      if (diag) {  // causal mask: key > q -> -inf (also covers skipped tiles)
#pragma unroll
        for (int nt = 0; nt < 4; ++nt)
#pragma unroll
          for (int reg = 0; reg < 4; ++reg) {
            const int key = nt * 16 + quad * 4 + reg;
            const int qq = w * 16 + l15;
            if (key > qq) s[nt][reg] = -1e30f;
          }
      }

      // online softmax (log2 domain): in-lane tree + 2 shfl_xor; defer-max.
      float pmax = -1e30f;
#pragma unroll
      for (int nt = 0; nt < 4; ++nt)
        pmax = fmaxf(pmax, fmaxf(fmaxf(s[nt][0], s[nt][1]), fmaxf(s[nt][2], s[nt][3])));
      pmax = fmaxf(pmax, __shfl_xor(pmax, 16));
      pmax = fmaxf(pmax, __shfl_xor(pmax, 32));
      float mn = m_;
      if (!__all(pmax <= m_ + 8.0f)) {  // wave-uniform branch
        mn = fmaxf(m_, pmax);
        const float alpha = exp2f(m_ - mn);
        m_ = mn;
        l_ *= alpha;
        float af[4];
#pragma unroll
        for (int reg = 0; reg < 4; ++reg) af[reg] = __shfl(alpha, quad * 4 + reg, 16);
#pragma unroll
        for (int nt = 0; nt < 8; ++nt)
#pragma unroll
          for (int reg = 0; reg < 4; ++reg) o[nt][reg] *= af[reg];
      }
      float rs = 0.f;
#pragma unroll
      for (int nt = 0; nt < 4; ++nt)
#pragma unroll
        for (int reg = 0; reg < 4; ++reg) {
          const float p_ = exp2f(s[nt][reg] - mn);
          s[nt][reg] = p_;
          rs += p_;
        }
      rs += __shfl_xor(rs, 16);
      rs += __shfl_xor(rs, 32);
      l_ += rs;

      // P pack: cvt_pk pairs consecutive keys (quad*4+2p, +1) for q=l15.
      // Store u32 at [row=l15][physcol = (nt*8+quad*2+p) ^ (h7<<2)].
      unsigned int* Pw32 = (unsigned int*)Ps[w];
#pragma unroll
      for (int nt = 0; nt < 4; ++nt)
#pragma unroll
        for (int p = 0; p < 2; ++p) {
          unsigned int u;
          asm("v_cvt_pk_bf16_f32 %0, %1, %2"
              : "=v"(u)
              : "v"(s[nt][2 * p]), "v"(s[nt][2 * p + 1]));
          Pw32[l15 * 32 + ((nt * 8 + quad * 2 + p) ^ (h7 << 2))] = u;
        }
      asm volatile("" ::: "memory");  // order P writes before P reads

      // O += P V. A = P: row = l15 (q), keys = ch2*32 + quad*8 .. +7
      //           B = V: col = d = nt*16+l15, keys natural.
      const int ch2max = (ntm >= 2) ? 1 : 0;
      __builtin_amdgcn_s_setprio(1);
#pragma unroll
      for (int ch2 = 0; ch2 < 2; ++ch2) {
        if (ch2 <= ch2max) {
          const bf16x8 pa =
              *(const bf16x8*)(Pw32 + l15 * 32 + (((ch2 * 16 + quad * 4) ^ (h7 << 2))));
          const int c = ch2 * 4 + quad;
#pragma unroll
          for (int nt = 0; nt < 8; ++nt) {
            const int d = nt * 16 + l15;
            const bf16x8 vv = *(const bf16x8*)&Vs[buf][d * 64 + ((c ^ (d & 7)) << 3)];
            o[nt] = mfma16(pa, vv, o[nt]);
          }
        }
      }
      __builtin_amdgcn_s_setprio(0);

      // single barrier per iter: next tile's loads (issued at top) now land.
      asm volatile("s_waitcnt vmcnt(0)\n\ts_barrier" ::: "memory");
      buf ^= 1;
    }

    // epilogue: normalize (l in O-layout via shfl) and store as (B*S, D) bf16
    float linv[4];
#pragma unroll
    for (int reg = 0; reg < 4; ++reg)
      linv[reg] = 1.0f / __shfl(l_, quad * 4 + reg, 16);
#pragma unroll
    for (int reg = 0; reg < 4; ++reg) {
      const int sq = qt * 64 + w * 16 + quad * 4 + reg;
      unsigned short* ob = Oa + (size_t)(b * SEQ + sq) * DMODEL + h * HD;
#pragma unroll
      for (int nt = 0; nt < 8; ++nt) ob[nt * 16 + l15] = f2bf(o[nt][reg] * linv[reg]);
    }
  }
}

extern "C" void kernel_launch(void* const* d_in, const int* in_sizes, int n_in,
                              void* d_out, int out_size, void* d_ws, size_t ws_size,
                              hipStream_t stream) {
  const float* x = (const float*)d_in[0];
  const float* Wq = (const float*)d_in[1];
  const float* Wk = (const float*)d_in[2];
  const float* Wv = (const float*)d_in[3];
  const float* Wo = (const float*)d_in[4];
  float* out = (float*)d_out;

  const size_t NX = (size_t)2 * SEQ * DMODEL;
  const size_t NW = (size_t)DMODEL * DMODEL;
  unsigned short* ws = (unsigned short*)d_ws;
  unsigned short* xb = ws;
  unsigned short* wqb = xb + NX;   // wq/wk/wv contiguous -> fused N=6144 B operand
  unsigned short* wkb = wqb + NW;
  unsigned short* wvb = wkb + NW;
  unsigned short* wob = wvb + NW;
  unsigned short* qb = wob + NW;  // (B,H,S,hd) permuted-hd, rope'd, *log2e/sqrt(hd)
  unsigned short* kb = qb + NX;   // (B,H,S,hd) permuted-hd, rope'd
  unsigned short* vb = kb + NX;   // (B,H,hd,S), natural key order
  unsigned short* ab = vb + NX;   // (B*S, D)
  float2* rtab = (float2*)(ab + NX);  // 2048 x 64 cos/sin (1 MB)

  cvt_all<<<25088, 256, 0, stream>>>(x, Wq, Wk, Wv, Wo, ws, rtab);
  gemm_pipe<0><<<dim3(32, 16), 512, 0, stream>>>(xb, wqb, qb, nullptr, rtab);
  attn_kernel<<<512, 256, 0, stream>>>(qb, kb, vb, ab);
  gemm_pipe<1><<<dim3(16, 16), 512, 0, stream>>>(ab, wob, nullptr, out, nullptr);
}